// Round 1
// baseline (294.568 us; speedup 1.0000x reference)
//
#include <hip/hip_runtime.h>

typedef __attribute__((ext_vector_type(8))) short short8_t;  // 8 bf16 (4 VGPRs)
typedef __attribute__((ext_vector_type(4))) float float4_t;  // MFMA C/D
typedef unsigned short u16;
typedef unsigned int u32;
typedef unsigned long long u64;

// ---------- helpers ----------
__device__ inline u16 f2bf(float x) {
  union { float f; u32 u; } v; v.f = x;
  u32 r = v.u + 0x7FFFu + ((v.u >> 16) & 1u);  // round-to-nearest-even
  return (u16)(r >> 16);
}
#if __has_builtin(__builtin_amdgcn_cvt_pk_bf16_f32)
typedef __attribute__((ext_vector_type(2))) __bf16 bf162_t;
__device__ inline u32 pk2(float a, float b) {   // v_cvt_pk_bf16_f32: low=a, high=b, RNE
  union { bf162_t v; u32 u; } cv;
  cv.v = __builtin_amdgcn_cvt_pk_bf16_f32(a, b);
  return cv.u;
}
#else
__device__ inline u32 pk2(float a, float b) {
  return (u32)f2bf(a) | ((u32)f2bf(b) << 16);
}
#endif

// ---------- fused prologue: X fp32->bf16 (blocks 0..4095), W transposes (4096..8191),
// ---------- per-batch all-ones mask flags (8192..8193, only when flags != null) ----------
__global__ __launch_bounds__(256) void prologue(const float* __restrict__ X,
                                                const float* __restrict__ Wq, const float* __restrict__ Wk,
                                                const float* __restrict__ Wv, const float* __restrict__ Wo,
                                                u16* __restrict__ Xb, u16* __restrict__ WqkvT,
                                                u16* __restrict__ WoT, const float* __restrict__ maskp,
                                                u32* __restrict__ flags) {
  __shared__ float tls[32][33];
  int bid = blockIdx.x;
  if (bid < 4096) {
    int i = bid * 256 + threadIdx.x;  // one float4 per thread
    float4_t x = ((const float4_t*)X)[i];
    union { u32 u[2]; u64 ll; } o;
    o.u[0] = pk2(x[0], x[1]);
    o.u[1] = pk2(x[2], x[3]);
    ((u64*)Xb)[i] = o.ll;
  } else if (bid < 8192) {
    int t = bid - 4096;
    int mat = t >> 10, tile = t & 1023;
    const float* W = (mat == 0) ? Wq : (mat == 1) ? Wk : (mat == 2) ? Wv : Wo;
    u16* WT = (mat < 3) ? WqkvT + ((size_t)mat << 20) : WoT;
    int tx = threadIdx.x & 31, ty = threadIdx.x >> 5;  // 32 x 8
    int c0 = (tile & 31) * 32, r0 = (tile >> 5) * 32;  // r0: k, c0: n
    #pragma unroll
    for (int i = 0; i < 4; ++i)
      tls[ty + i * 8][tx] = W[(r0 + ty + i * 8) * 1024 + c0 + tx];
    __syncthreads();
    #pragma unroll
    for (int i = 0; i < 4; ++i)
      WT[(size_t)(c0 + ty + i * 8) * 1024 + r0 + tx] = f2bf(tls[tx][ty + i * 8]);
  } else {
    // all-ones detection for attention mask, one block per batch
    int b = bid - 8192;
    const float* mb = maskp + (b << 11) + threadIdx.x * 8;
    bool ok = true;
    #pragma unroll
    for (int i = 0; i < 8; ++i) ok &= (mb[i] == 1.0f);
    u64 bal = __ballot(ok);
    int w = threadIdx.x >> 6;
    if ((threadIdx.x & 63) == 0) tls[0][w] = (bal == ~0ull) ? 1.0f : 0.0f;
    __syncthreads();
    if (threadIdx.x == 0)
      flags[b] = (tls[0][0] != 0.0f && tls[0][1] != 0.0f &&
                  tls[0][2] != 0.0f && tls[0][3] != 0.0f) ? 1u : 0u;
  }
}

// ---------- GEMM: 128x128 C-tile, 4 waves each 64x64, BK=64, VGPR-pipelined staging ----------
// mode 4 (fused QKV, 768 blocks): col block 0->Q(x0.125*log2e) o0 [B,H,S,64], 1->K o1,
//   2->V o2 [B,H,64,S] (transposed). mode 3 (O-proj, 256 blocks): fp32 out o0.
__global__ __launch_bounds__(256) void gemm128(const u16* __restrict__ A, const u16* __restrict__ BT,
                                               const float* __restrict__ bias0, const float* __restrict__ bias1,
                                               const float* __restrict__ bias2,
                                               void* __restrict__ o0, void* __restrict__ o1, void* __restrict__ o2,
                                               int mode) {
  __shared__ __align__(16) u16 Als[128 * 64];  // 16 KB
  __shared__ __align__(16) u16 Bls[128 * 64];  // 16 KB
  int g = blockIdx.x, m0t, n0t;
  if (mode == 4) {  // 768 blocks: panels of 16 m-tiles x 24 n-tiles
    int mh = g / 384, r = g - mh * 384;
    n0t = r >> 4;
    m0t = mh * 16 + (r & 15);
  } else {          // 256 blocks
    m0t = g & 31;
    n0t = g >> 5;
  }
  const int m0 = m0t * 128, n0 = n0t * 128;
  const int lane = threadIdx.x & 63, wave = threadIdx.x >> 6;
  const int quad = lane >> 4, c = lane & 15;
  const int wm = wave >> 1, wn = wave & 1;

  // staging lanes: 8 rows x 8 chunks(16B) per call; wave covers 32 rows via 4 calls
  const int srow = lane >> 3, schunk = lane & 7;
  int soff[4], dst[4];
  #pragma unroll
  for (int q = 0; q < 4; ++q) {
    int r = wave * 32 + q * 8 + srow;
    soff[q] = r * 1024 + (schunk << 3);                 // linear global
    dst[q]  = r * 64 + ((schunk ^ (r & 7)) << 3);       // XOR-swizzled LDS dest
  }
  const u16* gA = A + (size_t)m0 * 1024;
  const u16* gB = BT + (size_t)n0 * 1024;

  int ar[2][4], br[2][4];
  #pragma unroll
  for (int ko = 0; ko < 2; ++ko) {
    #pragma unroll
    for (int i = 0; i < 4; ++i) {
      int rowa = wm * 64 + i * 16 + c;
      ar[ko][i] = rowa * 64 + (((ko * 4 + quad) ^ (rowa & 7)) << 3);
      int rowb = wn * 64 + i * 16 + c;
      br[ko][i] = rowb * 64 + (((ko * 4 + quad) ^ (rowb & 7)) << 3);
    }
  }

  // prefetch slab 0 into VGPRs
  short8_t ra[4], rb[4];
  #pragma unroll
  for (int q = 0; q < 4; ++q) ra[q] = *(const short8_t*)(gA + soff[q]);
  #pragma unroll
  for (int q = 0; q < 4; ++q) rb[q] = *(const short8_t*)(gB + soff[q]);

  float4_t acc[4][4] = {};
  for (int k0 = 0; k0 < 1024; k0 += 64) {
    // commit prefetched slab to LDS
    #pragma unroll
    for (int q = 0; q < 4; ++q) *(short8_t*)&Als[dst[q]] = ra[q];
    #pragma unroll
    for (int q = 0; q < 4; ++q) *(short8_t*)&Bls[dst[q]] = rb[q];
    __syncthreads();
    // issue next slab's loads now; latency hides under the 32 MFMAs below
    if (k0 < 960) {
      #pragma unroll
      for (int q = 0; q < 4; ++q) ra[q] = *(const short8_t*)(gA + soff[q] + k0 + 64);
      #pragma unroll
      for (int q = 0; q < 4; ++q) rb[q] = *(const short8_t*)(gB + soff[q] + k0 + 64);
    }
    #pragma unroll
    for (int ko = 0; ko < 2; ++ko) {
      short8_t af[4], bfr[4];
      #pragma unroll
      for (int i = 0; i < 4; ++i) af[i] = *(const short8_t*)&Als[ar[ko][i]];
      #pragma unroll
      for (int j = 0; j < 4; ++j) bfr[j] = *(const short8_t*)&Bls[br[ko][j]];
      #pragma unroll
      for (int i = 0; i < 4; ++i)
        #pragma unroll
        for (int j = 0; j < 4; ++j)
          acc[i][j] = __builtin_amdgcn_mfma_f32_16x16x32_bf16(af[i], bfr[j], acc[i][j], 0, 0, 0);
    }
    __syncthreads();  // all reads done before next commit (single LDS buffer)
  }

  const int mrow = m0 + wm * 64, ncol = n0 + wn * 64;
  if (mode == 3) {
    float* o = (float*)o0;
    #pragma unroll
    for (int i = 0; i < 4; ++i) {
      #pragma unroll
      for (int j = 0; j < 4; ++j) {
        int colb = ncol + j * 16 + c;
        float bv = bias0[colb];
        int rowb = mrow + i * 16 + quad * 4;
        #pragma unroll
        for (int r = 0; r < 4; ++r)
          o[(size_t)(rowb + r) * 1024 + colb] = acc[i][j][r] + bv;
      }
    }
  } else {
    #pragma unroll
    for (int j = 0; j < 4; ++j) {
      int colb = ncol + j * 16 + c;     // 0..3071
      int which = colb >> 10;           // 0:Q 1:K 2:V (uniform per j)
      int n1 = colb & 1023, h = n1 >> 6, d = n1 & 63;
      const float* bp = (which == 0) ? bias0 : (which == 1 ? bias1 : bias2);
      float bv = bp[n1];
      #pragma unroll
      for (int i = 0; i < 4; ++i) {
        int rowb = mrow + i * 16 + quad * 4;
        int b = rowb >> 11, s = rowb & 2047;
        if (which == 2) {
          u16* o = (u16*)o2 + (((size_t)(b * 16 + h) * 64 + d) * 2048 + s);
          union { u32 u[2]; u64 ll; } ov;
          ov.u[0] = pk2(acc[i][j][0] + bv, acc[i][j][1] + bv);
          ov.u[1] = pk2(acc[i][j][2] + bv, acc[i][j][3] + bv);
          *(u64*)o = ov.ll;
        } else {
          // Q pre-scale folds softmax's LOG2E: 0.125 * 1.4426950408889634
          float sc = (which == 0) ? 0.18033688011112042f : 1.0f;
          u16* o = (u16*)((which == 0) ? o0 : o1);
          #pragma unroll
          for (int r = 0; r < 4; ++r)
            o[(((size_t)(b * 16 + h) * 2048 + (s + r)) << 6) + d] = f2bf((acc[i][j][r] + bv) * sc);
        }
      }
    }
  }
}

// P^T C-layout -> 16x16x32 B-operand layout via packed-bf16 shuffles (proven r2-r9)
__device__ inline short8_t p_to_b32(const float* p, int quad, int c) {
  u32 pk0[2] = {pk2(p[0], p[1]), pk2(p[2], p[3])};
  u32 pk1[2] = {pk2(p[4], p[5]), pk2(p[6], p[7])};
  int base = ((quad & 1) * 2) * 16 + c;
  union { u32 u[4]; short8_t v; } pf;
  #pragma unroll
  for (int x = 0; x < 4; ++x) {
    int src = base + ((x >> 1) << 4);
    int v0 = __shfl((int)pk0[x & 1], src);
    int v1 = __shfl((int)pk1[x & 1], src);
    pf.u[x] = (quad < 2) ? (u32)v0 : (u32)v1;
  }
  return pf.v;
}

// ---------- flash attention v2: barrier-free waves, direct L1/L2 operand reads ----------
// Q,K: [B,H,S,64] bf16 (Q pre-scaled by 0.125*log2e); VT: [B,H,64,S]; ctx: [B,S,1024] bf16.
// Grid 2048 x 256. Block = (bh, m, p2): m = key-tile count-1 (0..31), heavy-first.
// 4 waves = 2 pairs; pair pr handles q16-tile j = 4m + p2*2 + pr; the two waves of a
// pair split the key range [0, m] into halves (fixed-base softmax => partial (O,l)
// combine by simple ADDITION -- no rescale). All 4 waves have identical work (m+1)/2,
// so there is no intra-block convoy, and the main loop has ZERO barriers: K and V
// fragments are read directly from global (L1-hot: the 2 same-half waves of a block
// walk identical K/V lines; L2-hot: bh<->XCD affinity keeps 4 bh x 512KB in each XCD L2).
// Combine: half1 writes (O,l) partials to 8.8KB LDS, one __syncthreads, half0 adds,
// normalizes, stores. Mask all-ones fast path on a uniform per-block flag.
__global__ __launch_bounds__(256, 6) void attn_kernel(const u16* __restrict__ Q, const u16* __restrict__ K,
                                                      const u16* __restrict__ VT, const float* __restrict__ mask,
                                                      const u32* __restrict__ flags, u16* __restrict__ ctx) {
  __shared__ float Ols[2][64][17];  // [pair][d][q] f32 partial, +1 pad vs bank conflicts
  __shared__ float Lls[2][16];      // [pair][q] partial denominators
  const float C1 = 10000.0f * 1.4426950408889634f;
  int w = threadIdx.x >> 6, lane = threadIdx.x & 63;
  int quad = lane >> 4, c = lane & 15;
  int g = blockIdx.x;
  int bh = (g & 7) * 4 + ((g >> 3) & 3);   // XCD L2 affinity
  int u = g >> 5;                          // 0..63
  int m = 31 - (u >> 1);                   // heavy blocks dispatch first
  int p2 = u & 1;
  int pr = w >> 1, half = w & 1;
  int jj = p2 * 2 + pr;                    // j & 3
  int j = (m << 2) + jj;                   // q16-tile index (0..127)
  int b = bh >> 4, h = bh & 15;
  bool ones = flags && (flags[b] != 0);

  const u16* Kp = K + ((size_t)bh << 17);
  const u16* Vp = VT + ((size_t)bh << 17);
  const float* mp = mask + (b << 11);

  // Q^T B-operand fragment (16 queries per wave)
  const u16* Qp = Q + (((size_t)bh * 2048 + j * 16 + c) << 6) + quad * 8;
  short8_t qf0 = *(const short8_t*)(Qp);
  short8_t qf1 = *(const short8_t*)(Qp + 32);

  // per-lane fragment bases (A-frag: row = c, k-chunk = quad*8)
  const u16* kb0 = Kp + c * 64 + quad * 8;
  const u16* vb0 = Vp + c * 2048 + quad * 8;

  int n = m + 1, h0 = n >> 1;
  int lo = half ? h0 : 0, hi = half ? n : h0;
  int tq = jj * 16 + c - quad * 4;         // causal threshold (diag tile only)

  float4_t O[4] = {};
  float l = 0.0f;

  for (int t = lo; t < hi; ++t) {
    int kb = t << 6;
    // ---- K fragments direct from L1/L2 ----
    short8_t kf[4][2];
    #pragma unroll
    for (int kg = 0; kg < 4; ++kg)
      #pragma unroll
      for (int ko = 0; ko < 2; ++ko)
        kf[kg][ko] = *(const short8_t*)(kb0 + (kb + kg * 16) * 64 + ko * 32);
    // ---- S^T = K_tile @ Q^T (8 MFMA) ----
    float4_t s[4];
    #pragma unroll
    for (int kg = 0; kg < 4; ++kg) {
      float4_t a = {};
      a = __builtin_amdgcn_mfma_f32_16x16x32_bf16(kf[kg][0], qf0, a, 0, 0, 0);
      a = __builtin_amdgcn_mfma_f32_16x16x32_bf16(kf[kg][1], qf1, a, 0, 0, 0);
      s[kg] = a;
    }
    // ---- mask + fixed-base softmax (log2e pre-folded into Q) + C->B transform ----
    float4_t mpl[4];
    if (!ones) {
      #pragma unroll
      for (int kg = 0; kg < 4; ++kg)
        mpl[kg] = (*(const float4_t*)(mp + kb + kg * 16 + quad * 4) - 1.0f) * C1;
    }
    bool diag = (t == m);
    short8_t pf[2];
    #pragma unroll
    for (int kc = 0; kc < 2; ++kc) {
      float p[8];
      #pragma unroll
      for (int e = 0; e < 8; ++e) {
        int kg = kc * 2 + (e >> 2);
        p[e] = s[kg][e & 3];
        if (!ones) p[e] += mpl[kg][e & 3];
      }
      if (diag) {
        #pragma unroll
        for (int e = 0; e < 8; ++e) {
          int Ce = kc * 32 + ((e >> 2) << 4) + (e & 3);  // compile-time per e,kc
          p[e] = (Ce > tq) ? -50.0f : p[e];
        }
      }
      #pragma unroll
      for (int e = 0; e < 8; ++e) {
        float pe = exp2f(p[e]);
        p[e] = pe;
        l += pe;
      }
      pf[kc] = p_to_b32(p, quad, c);
    }
    // ---- ctx^T += V^T_tile @ P^T (8 MFMA, V fragments direct; compiler hoists loads) ----
    #pragma unroll
    for (int dblk = 0; dblk < 4; ++dblk) {
      short8_t v0 = *(const short8_t*)(vb0 + dblk * 16 * 2048 + kb);
      short8_t v1 = *(const short8_t*)(vb0 + dblk * 16 * 2048 + kb + 32);
      O[dblk] = __builtin_amdgcn_mfma_f32_16x16x32_bf16(v0, pf[0], O[dblk], 0, 0, 0);
      O[dblk] = __builtin_amdgcn_mfma_f32_16x16x32_bf16(v1, pf[1], O[dblk], 0, 0, 0);
    }
  }

  // ---- pairwise additive combine + normalize + store ----
  l += __shfl_xor(l, 16);
  l += __shfl_xor(l, 32);
  if (half) {
    #pragma unroll
    for (int dblk = 0; dblk < 4; ++dblk)
      #pragma unroll
      for (int r = 0; r < 4; ++r)
        Ols[pr][dblk * 16 + quad * 4 + r][c] = O[dblk][r];
    if (quad == 0) Lls[pr][c] = l;
  }
  __syncthreads();
  if (half) return;
  float rl = 1.0f / (l + Lls[pr][c]);
  u16* op = ctx + ((size_t)(b * 2048 + j * 16 + c) * 1024 + h * 64 + quad * 4);
  #pragma unroll
  for (int dblk = 0; dblk < 4; ++dblk) {
    float o0v = (O[dblk][0] + Ols[pr][dblk * 16 + quad * 4 + 0][c]) * rl;
    float o1v = (O[dblk][1] + Ols[pr][dblk * 16 + quad * 4 + 1][c]) * rl;
    float o2v = (O[dblk][2] + Ols[pr][dblk * 16 + quad * 4 + 2][c]) * rl;
    float o3v = (O[dblk][3] + Ols[pr][dblk * 16 + quad * 4 + 3][c]) * rl;
    union { u32 uu[2]; u64 ll; } ov;
    ov.uu[0] = pk2(o0v, o1v);
    ov.uu[1] = pk2(o2v, o3v);
    *(u64*)(op + dblk * 16) = ov.ll;
  }
}

// ---------- launch ----------
extern "C" void kernel_launch(void* const* d_in, const int* in_sizes, int n_in,
                              void* d_out, int out_size, void* d_ws, size_t ws_size,
                              hipStream_t stream) {
  const float* X    = (const float*)d_in[0];
  const float* mask = (const float*)d_in[1];
  const float* Wq   = (const float*)d_in[2];
  const float* bq   = (const float*)d_in[3];
  const float* Wk   = (const float*)d_in[4];
  const float* bk   = (const float*)d_in[5];
  const float* Wv   = (const float*)d_in[6];
  const float* bv   = (const float*)d_in[7];
  const float* Wo   = (const float*)d_in[8];
  const float* bo   = (const float*)d_in[9];

  char* w = (char*)d_ws;
  u16* Xb     = (u16*)(w);                 // 8 MB  [4096,1024] bf16
  u16* WqkvT  = (u16*)(w + (8ull  << 20)); // 6 MB  [3072,1024] bf16 (Q|K|V transposed)
  u16* WoT    = (u16*)(w + (14ull << 20)); // 2 MB  [1024,1024] bf16
  u16* Qb     = (u16*)(w + (16ull << 20)); // 8 MB [B,H,S,64]
  u16* Kb     = (u16*)(w + (24ull << 20)); // 8 MB [B,H,S,64]
  u16* VTb    = (u16*)(w + (32ull << 20)); // 8 MB [B,H,64,S]
  u16* Ctx    = (u16*)(w + (40ull << 20)); // 8 MB [4096,1024]
  u32* flags  = (ws_size >= (48ull << 20) + 8) ? (u32*)(w + (48ull << 20)) : nullptr;

  prologue<<<flags ? 8194 : 8192, 256, 0, stream>>>(X, Wq, Wk, Wv, Wo, Xb, WqkvT, WoT, mask, flags);
  gemm128<<<768, 256, 0, stream>>>(Xb, WqkvT, bq, bk, bv, Qb, Kb, VTb, 4);
  attn_kernel<<<2048, 256, 0, stream>>>(Qb, Kb, VTb, mask, flags, Ctx);
  gemm128<<<256, 256, 0, stream>>>(Ctx, WoT, bo, bo, bo, d_out, d_out, d_out, 3);
}

// Round 2
// 267.034 us; speedup vs baseline: 1.1031x; 1.1031x over previous
//
#include <hip/hip_runtime.h>

typedef __attribute__((ext_vector_type(8))) short short8_t;  // 8 bf16 (4 VGPRs)
typedef __attribute__((ext_vector_type(4))) float float4_t;  // MFMA C/D
typedef unsigned short u16;
typedef unsigned int u32;
typedef unsigned long long u64;

// ---------- helpers ----------
__device__ inline u16 f2bf(float x) {
  union { float f; u32 u; } v; v.f = x;
  u32 r = v.u + 0x7FFFu + ((v.u >> 16) & 1u);  // round-to-nearest-even
  return (u16)(r >> 16);
}
#if __has_builtin(__builtin_amdgcn_cvt_pk_bf16_f32)
typedef __attribute__((ext_vector_type(2))) __bf16 bf162_t;
__device__ inline u32 pk2(float a, float b) {   // v_cvt_pk_bf16_f32: low=a, high=b, RNE
  union { bf162_t v; u32 u; } cv;
  cv.v = __builtin_amdgcn_cvt_pk_bf16_f32(a, b);
  return cv.u;
}
#else
__device__ inline u32 pk2(float a, float b) {
  return (u32)f2bf(a) | ((u32)f2bf(b) << 16);
}
#endif

// ---------- fused prologue: X fp32->bf16 (blocks 0..4095), W transposes (4096..8191),
// ---------- per-batch all-ones mask flags (8192..8193, only when flags != null) ----------
__global__ __launch_bounds__(256) void prologue(const float* __restrict__ X,
                                                const float* __restrict__ Wq, const float* __restrict__ Wk,
                                                const float* __restrict__ Wv, const float* __restrict__ Wo,
                                                u16* __restrict__ Xb, u16* __restrict__ WqkvT,
                                                u16* __restrict__ WoT, const float* __restrict__ maskp,
                                                u32* __restrict__ flags) {
  __shared__ float tls[32][33];
  int bid = blockIdx.x;
  if (bid < 4096) {
    int i = bid * 256 + threadIdx.x;  // one float4 per thread
    float4_t x = ((const float4_t*)X)[i];
    union { u32 u[2]; u64 ll; } o;
    o.u[0] = pk2(x[0], x[1]);
    o.u[1] = pk2(x[2], x[3]);
    ((u64*)Xb)[i] = o.ll;
  } else if (bid < 8192) {
    int t = bid - 4096;
    int mat = t >> 10, tile = t & 1023;
    const float* W = (mat == 0) ? Wq : (mat == 1) ? Wk : (mat == 2) ? Wv : Wo;
    u16* WT = (mat < 3) ? WqkvT + ((size_t)mat << 20) : WoT;
    int tx = threadIdx.x & 31, ty = threadIdx.x >> 5;  // 32 x 8
    int c0 = (tile & 31) * 32, r0 = (tile >> 5) * 32;  // r0: k, c0: n
    #pragma unroll
    for (int i = 0; i < 4; ++i)
      tls[ty + i * 8][tx] = W[(r0 + ty + i * 8) * 1024 + c0 + tx];
    __syncthreads();
    #pragma unroll
    for (int i = 0; i < 4; ++i)
      WT[(size_t)(c0 + ty + i * 8) * 1024 + r0 + tx] = f2bf(tls[tx][ty + i * 8]);
  } else {
    // all-ones detection for attention mask, one block per batch
    int b = bid - 8192;
    const float* mb = maskp + (b << 11) + threadIdx.x * 8;
    bool ok = true;
    #pragma unroll
    for (int i = 0; i < 8; ++i) ok &= (mb[i] == 1.0f);
    u64 bal = __ballot(ok);
    int w = threadIdx.x >> 6;
    if ((threadIdx.x & 63) == 0) tls[0][w] = (bal == ~0ull) ? 1.0f : 0.0f;
    __syncthreads();
    if (threadIdx.x == 0)
      flags[b] = (tls[0][0] != 0.0f && tls[0][1] != 0.0f &&
                  tls[0][2] != 0.0f && tls[0][3] != 0.0f) ? 1u : 0u;
  }
}

// ---------- GEMM: 128x128 C-tile, 4 waves each 64x64, BK=64, VGPR-pipelined staging ----------
// mode 4 (fused QKV, 768 blocks): col block 0->Q(x0.125*log2e) o0 [B,H,S,64], 1->K o1,
//   2->V o2 [B,H,64,S] (transposed). mode 3 (O-proj, 256 blocks): fp32 out o0.
__global__ __launch_bounds__(256) void gemm128(const u16* __restrict__ A, const u16* __restrict__ BT,
                                               const float* __restrict__ bias0, const float* __restrict__ bias1,
                                               const float* __restrict__ bias2,
                                               void* __restrict__ o0, void* __restrict__ o1, void* __restrict__ o2,
                                               int mode) {
  __shared__ __align__(16) u16 Als[128 * 64];  // 16 KB
  __shared__ __align__(16) u16 Bls[128 * 64];  // 16 KB
  int g = blockIdx.x, m0t, n0t;
  if (mode == 4) {  // 768 blocks: panels of 16 m-tiles x 24 n-tiles
    int mh = g / 384, r = g - mh * 384;
    n0t = r >> 4;
    m0t = mh * 16 + (r & 15);
  } else {          // 256 blocks
    m0t = g & 31;
    n0t = g >> 5;
  }
  const int m0 = m0t * 128, n0 = n0t * 128;
  const int lane = threadIdx.x & 63, wave = threadIdx.x >> 6;
  const int quad = lane >> 4, c = lane & 15;
  const int wm = wave >> 1, wn = wave & 1;

  // staging lanes: 8 rows x 8 chunks(16B) per call; wave covers 32 rows via 4 calls
  const int srow = lane >> 3, schunk = lane & 7;
  int soff[4], dst[4];
  #pragma unroll
  for (int q = 0; q < 4; ++q) {
    int r = wave * 32 + q * 8 + srow;
    soff[q] = r * 1024 + (schunk << 3);                 // linear global
    dst[q]  = r * 64 + ((schunk ^ (r & 7)) << 3);       // XOR-swizzled LDS dest
  }
  const u16* gA = A + (size_t)m0 * 1024;
  const u16* gB = BT + (size_t)n0 * 1024;

  int ar[2][4], br[2][4];
  #pragma unroll
  for (int ko = 0; ko < 2; ++ko) {
    #pragma unroll
    for (int i = 0; i < 4; ++i) {
      int rowa = wm * 64 + i * 16 + c;
      ar[ko][i] = rowa * 64 + (((ko * 4 + quad) ^ (rowa & 7)) << 3);
      int rowb = wn * 64 + i * 16 + c;
      br[ko][i] = rowb * 64 + (((ko * 4 + quad) ^ (rowb & 7)) << 3);
    }
  }

  // prefetch slab 0 into VGPRs
  short8_t ra[4], rb[4];
  #pragma unroll
  for (int q = 0; q < 4; ++q) ra[q] = *(const short8_t*)(gA + soff[q]);
  #pragma unroll
  for (int q = 0; q < 4; ++q) rb[q] = *(const short8_t*)(gB + soff[q]);

  float4_t acc[4][4] = {};
  for (int k0 = 0; k0 < 1024; k0 += 64) {
    // commit prefetched slab to LDS
    #pragma unroll
    for (int q = 0; q < 4; ++q) *(short8_t*)&Als[dst[q]] = ra[q];
    #pragma unroll
    for (int q = 0; q < 4; ++q) *(short8_t*)&Bls[dst[q]] = rb[q];
    __syncthreads();
    // issue next slab's loads now; latency hides under the 32 MFMAs below
    if (k0 < 960) {
      #pragma unroll
      for (int q = 0; q < 4; ++q) ra[q] = *(const short8_t*)(gA + soff[q] + k0 + 64);
      #pragma unroll
      for (int q = 0; q < 4; ++q) rb[q] = *(const short8_t*)(gB + soff[q] + k0 + 64);
    }
    #pragma unroll
    for (int ko = 0; ko < 2; ++ko) {
      short8_t af[4], bfr[4];
      #pragma unroll
      for (int i = 0; i < 4; ++i) af[i] = *(const short8_t*)&Als[ar[ko][i]];
      #pragma unroll
      for (int j = 0; j < 4; ++j) bfr[j] = *(const short8_t*)&Bls[br[ko][j]];
      #pragma unroll
      for (int i = 0; i < 4; ++i)
        #pragma unroll
        for (int j = 0; j < 4; ++j)
          acc[i][j] = __builtin_amdgcn_mfma_f32_16x16x32_bf16(af[i], bfr[j], acc[i][j], 0, 0, 0);
    }
    __syncthreads();  // all reads done before next commit (single LDS buffer)
  }

  const int mrow = m0 + wm * 64, ncol = n0 + wn * 64;
  if (mode == 3) {
    float* o = (float*)o0;
    #pragma unroll
    for (int i = 0; i < 4; ++i) {
      #pragma unroll
      for (int j = 0; j < 4; ++j) {
        int colb = ncol + j * 16 + c;
        float bv = bias0[colb];
        int rowb = mrow + i * 16 + quad * 4;
        #pragma unroll
        for (int r = 0; r < 4; ++r)
          o[(size_t)(rowb + r) * 1024 + colb] = acc[i][j][r] + bv;
      }
    }
  } else {
    #pragma unroll
    for (int j = 0; j < 4; ++j) {
      int colb = ncol + j * 16 + c;     // 0..3071
      int which = colb >> 10;           // 0:Q 1:K 2:V (uniform per j)
      int n1 = colb & 1023, h = n1 >> 6, d = n1 & 63;
      const float* bp = (which == 0) ? bias0 : (which == 1 ? bias1 : bias2);
      float bv = bp[n1];
      #pragma unroll
      for (int i = 0; i < 4; ++i) {
        int rowb = mrow + i * 16 + quad * 4;
        int b = rowb >> 11, s = rowb & 2047;
        if (which == 2) {
          u16* o = (u16*)o2 + (((size_t)(b * 16 + h) * 64 + d) * 2048 + s);
          union { u32 u[2]; u64 ll; } ov;
          ov.u[0] = pk2(acc[i][j][0] + bv, acc[i][j][1] + bv);
          ov.u[1] = pk2(acc[i][j][2] + bv, acc[i][j][3] + bv);
          *(u64*)o = ov.ll;
        } else {
          // Q pre-scale folds softmax's LOG2E: 0.125 * 1.4426950408889634
          float sc = (which == 0) ? 0.18033688011112042f : 1.0f;
          u16* o = (u16*)((which == 0) ? o0 : o1);
          #pragma unroll
          for (int r = 0; r < 4; ++r)
            o[(((size_t)(b * 16 + h) * 2048 + (s + r)) << 6) + d] = f2bf((acc[i][j][r] + bv) * sc);
        }
      }
    }
  }
}

// P^T C-layout -> 16x16x32 B-operand layout via packed-bf16 shuffles (proven r2-r9)
__device__ inline short8_t p_to_b32(const float* p, int quad, int c) {
  u32 pk0[2] = {pk2(p[0], p[1]), pk2(p[2], p[3])};
  u32 pk1[2] = {pk2(p[4], p[5]), pk2(p[6], p[7])};
  int base = ((quad & 1) * 2) * 16 + c;
  union { u32 u[4]; short8_t v; } pf;
  #pragma unroll
  for (int x = 0; x < 4; ++x) {
    int src = base + ((x >> 1) << 4);
    int v0 = __shfl((int)pk0[x & 1], src);
    int v1 = __shfl((int)pk1[x & 1], src);
    pf.u[x] = (quad < 2) ? (u32)v0 : (u32)v1;
  }
  return pf.v;
}

// ---------- flash attention v2.1: barrier-free waves, direct L1/L2 operand reads ----------
// Q,K: [B,H,S,64] bf16 (Q pre-scaled by 0.125*log2e); VT: [B,H,64,S]; ctx: [B,S,1024] bf16.
// Grid 2048 x 256. Block = (bh, m, p2): m = key-tile count-1 (0..31), heavy-first.
// 4 waves = 2 pairs; pair pr handles q16-tile j = 4m + p2*2 + pr; the two waves of a
// pair split the key range [0, m] into halves (fixed-base softmax => partial (O,l)
// combine by simple ADDITION -- no rescale). All 4 waves have identical work (m+1)/2,
// so there is no intra-block convoy, and the main loop has ZERO barriers.
// r1 lesson: __launch_bounds__(256,6) capped VGPR at 40 -> full spill (WRITE_SIZE
// 42.5MB of scratch, MfmaUtil 4.4%). Live set is ~95 regs; (256,4) gives the 128-reg
// budget (4 waves/EU, 16 waves/CU) with zero spill.
__global__ __launch_bounds__(256, 4) void attn_kernel(const u16* __restrict__ Q, const u16* __restrict__ K,
                                                      const u16* __restrict__ VT, const float* __restrict__ mask,
                                                      const u32* __restrict__ flags, u16* __restrict__ ctx) {
  __shared__ float Ols[2][64][17];  // [pair][d][q] f32 partial, +1 pad vs bank conflicts
  __shared__ float Lls[2][16];      // [pair][q] partial denominators
  const float C1 = 10000.0f * 1.4426950408889634f;
  int w = threadIdx.x >> 6, lane = threadIdx.x & 63;
  int quad = lane >> 4, c = lane & 15;
  int g = blockIdx.x;
  int bh = (g & 7) * 4 + ((g >> 3) & 3);   // XCD L2 affinity
  int u = g >> 5;                          // 0..63
  int m = 31 - (u >> 1);                   // heavy blocks dispatch first
  int p2 = u & 1;
  int pr = w >> 1, half = w & 1;
  int jj = p2 * 2 + pr;                    // j & 3
  int j = (m << 2) + jj;                   // q16-tile index (0..127)
  int b = bh >> 4, h = bh & 15;
  bool ones = flags && (flags[b] != 0);

  const u16* Kp = K + ((size_t)bh << 17);
  const u16* Vp = VT + ((size_t)bh << 17);
  const float* mp = mask + (b << 11);

  // Q^T B-operand fragment (16 queries per wave)
  const u16* Qp = Q + (((size_t)bh * 2048 + j * 16 + c) << 6) + quad * 8;
  short8_t qf0 = *(const short8_t*)(Qp);
  short8_t qf1 = *(const short8_t*)(Qp + 32);

  // per-lane fragment bases (A-frag: row = c, k-chunk = quad*8)
  const u16* kb0 = Kp + c * 64 + quad * 8;
  const u16* vb0 = Vp + c * 2048 + quad * 8;

  int n = m + 1, h0 = n >> 1;
  int lo = half ? h0 : 0, hi = half ? n : h0;
  int tq = jj * 16 + c - quad * 4;         // causal threshold (diag tile only)

  float4_t O[4] = {};
  float l = 0.0f;

  for (int t = lo; t < hi; ++t) {
    int kb = t << 6;
    // ---- K fragments direct from L1/L2 ----
    short8_t kf[4][2];
    #pragma unroll
    for (int kg = 0; kg < 4; ++kg)
      #pragma unroll
      for (int ko = 0; ko < 2; ++ko)
        kf[kg][ko] = *(const short8_t*)(kb0 + (kb + kg * 16) * 64 + ko * 32);
    // ---- S^T = K_tile @ Q^T (8 MFMA) ----
    float4_t s[4];
    #pragma unroll
    for (int kg = 0; kg < 4; ++kg) {
      float4_t a = {};
      a = __builtin_amdgcn_mfma_f32_16x16x32_bf16(kf[kg][0], qf0, a, 0, 0, 0);
      a = __builtin_amdgcn_mfma_f32_16x16x32_bf16(kf[kg][1], qf1, a, 0, 0, 0);
      s[kg] = a;
    }
    // ---- mask + fixed-base softmax (log2e pre-folded into Q) + C->B transform ----
    float4_t mpl[4];
    if (!ones) {
      #pragma unroll
      for (int kg = 0; kg < 4; ++kg)
        mpl[kg] = (*(const float4_t*)(mp + kb + kg * 16 + quad * 4) - 1.0f) * C1;
    }
    bool diag = (t == m);
    short8_t pf[2];
    #pragma unroll
    for (int kc = 0; kc < 2; ++kc) {
      float p[8];
      #pragma unroll
      for (int e = 0; e < 8; ++e) {
        int kg = kc * 2 + (e >> 2);
        p[e] = s[kg][e & 3];
        if (!ones) p[e] += mpl[kg][e & 3];
      }
      if (diag) {
        #pragma unroll
        for (int e = 0; e < 8; ++e) {
          int Ce = kc * 32 + ((e >> 2) << 4) + (e & 3);  // compile-time per e,kc
          p[e] = (Ce > tq) ? -50.0f : p[e];
        }
      }
      #pragma unroll
      for (int e = 0; e < 8; ++e) {
        float pe = exp2f(p[e]);
        p[e] = pe;
        l += pe;
      }
      pf[kc] = p_to_b32(p, quad, c);
    }
    // ---- ctx^T += V^T_tile @ P^T (8 MFMA, V fragments direct; compiler hoists loads) ----
    #pragma unroll
    for (int dblk = 0; dblk < 4; ++dblk) {
      short8_t v0 = *(const short8_t*)(vb0 + dblk * 16 * 2048 + kb);
      short8_t v1 = *(const short8_t*)(vb0 + dblk * 16 * 2048 + kb + 32);
      O[dblk] = __builtin_amdgcn_mfma_f32_16x16x32_bf16(v0, pf[0], O[dblk], 0, 0, 0);
      O[dblk] = __builtin_amdgcn_mfma_f32_16x16x32_bf16(v1, pf[1], O[dblk], 0, 0, 0);
    }
  }

  // ---- pairwise additive combine + normalize + store ----
  l += __shfl_xor(l, 16);
  l += __shfl_xor(l, 32);
  if (half) {
    #pragma unroll
    for (int dblk = 0; dblk < 4; ++dblk)
      #pragma unroll
      for (int r = 0; r < 4; ++r)
        Ols[pr][dblk * 16 + quad * 4 + r][c] = O[dblk][r];
    if (quad == 0) Lls[pr][c] = l;
  }
  __syncthreads();
  if (half) return;
  float rl = 1.0f / (l + Lls[pr][c]);
  u16* op = ctx + ((size_t)(b * 2048 + j * 16 + c) * 1024 + h * 64 + quad * 4);
  #pragma unroll
  for (int dblk = 0; dblk < 4; ++dblk) {
    float o0v = (O[dblk][0] + Ols[pr][dblk * 16 + quad * 4 + 0][c]) * rl;
    float o1v = (O[dblk][1] + Ols[pr][dblk * 16 + quad * 4 + 1][c]) * rl;
    float o2v = (O[dblk][2] + Ols[pr][dblk * 16 + quad * 4 + 2][c]) * rl;
    float o3v = (O[dblk][3] + Ols[pr][dblk * 16 + quad * 4 + 3][c]) * rl;
    union { u32 uu[2]; u64 ll; } ov;
    ov.uu[0] = pk2(o0v, o1v);
    ov.uu[1] = pk2(o2v, o3v);
    *(u64*)(op + dblk * 16) = ov.ll;
  }
}

// ---------- launch ----------
extern "C" void kernel_launch(void* const* d_in, const int* in_sizes, int n_in,
                              void* d_out, int out_size, void* d_ws, size_t ws_size,
                              hipStream_t stream) {
  const float* X    = (const float*)d_in[0];
  const float* mask = (const float*)d_in[1];
  const float* Wq   = (const float*)d_in[2];
  const float* bq   = (const float*)d_in[3];
  const float* Wk   = (const float*)d_in[4];
  const float* bk   = (const float*)d_in[5];
  const float* Wv   = (const float*)d_in[6];
  const float* bv   = (const float*)d_in[7];
  const float* Wo   = (const float*)d_in[8];
  const float* bo   = (const float*)d_in[9];

  char* w = (char*)d_ws;
  u16* Xb     = (u16*)(w);                 // 8 MB  [4096,1024] bf16
  u16* WqkvT  = (u16*)(w + (8ull  << 20)); // 6 MB  [3072,1024] bf16 (Q|K|V transposed)
  u16* WoT    = (u16*)(w + (14ull << 20)); // 2 MB  [1024,1024] bf16
  u16* Qb     = (u16*)(w + (16ull << 20)); // 8 MB [B,H,S,64]
  u16* Kb     = (u16*)(w + (24ull << 20)); // 8 MB [B,H,S,64]
  u16* VTb    = (u16*)(w + (32ull << 20)); // 8 MB [B,H,64,S]
  u16* Ctx    = (u16*)(w + (40ull << 20)); // 8 MB [4096,1024]
  u32* flags  = (ws_size >= (48ull << 20) + 8) ? (u32*)(w + (48ull << 20)) : nullptr;

  prologue<<<flags ? 8194 : 8192, 256, 0, stream>>>(X, Wq, Wk, Wv, Wo, Xb, WqkvT, WoT, mask, flags);
  gemm128<<<768, 256, 0, stream>>>(Xb, WqkvT, bq, bk, bv, Qb, Kb, VTb, 4);
  attn_kernel<<<2048, 256, 0, stream>>>(Qb, Kb, VTb, mask, flags, Ctx);
  gemm128<<<256, 256, 0, stream>>>(Ctx, WoT, bo, bo, bo, d_out, d_out, d_out, 3);
}

// Round 3
// 185.661 us; speedup vs baseline: 1.5866x; 1.4383x over previous
//
#include <hip/hip_runtime.h>

typedef __attribute__((ext_vector_type(8))) short short8_t;  // 8 bf16 (4 VGPRs)
typedef __attribute__((ext_vector_type(4))) float float4_t;  // MFMA C/D
typedef unsigned short u16;
typedef unsigned int u32;
typedef unsigned long long u64;

// ---------- helpers ----------
__device__ inline u16 f2bf(float x) {
  union { float f; u32 u; } v; v.f = x;
  u32 r = v.u + 0x7FFFu + ((v.u >> 16) & 1u);  // round-to-nearest-even
  return (u16)(r >> 16);
}
#if __has_builtin(__builtin_amdgcn_cvt_pk_bf16_f32)
typedef __attribute__((ext_vector_type(2))) __bf16 bf162_t;
__device__ inline u32 pk2(float a, float b) {   // v_cvt_pk_bf16_f32: low=a, high=b, RNE
  union { bf162_t v; u32 u; } cv;
  cv.v = __builtin_amdgcn_cvt_pk_bf16_f32(a, b);
  return cv.u;
}
#else
__device__ inline u32 pk2(float a, float b) {
  return (u32)f2bf(a) | ((u32)f2bf(b) << 16);
}
#endif

// ---------- fused prologue: X fp32->bf16 (blocks 0..4095), W transposes (4096..8191),
// ---------- per-batch all-ones mask flags (8192..8193, only when flags != null) ----------
__global__ __launch_bounds__(256) void prologue(const float* __restrict__ X,
                                                const float* __restrict__ Wq, const float* __restrict__ Wk,
                                                const float* __restrict__ Wv, const float* __restrict__ Wo,
                                                u16* __restrict__ Xb, u16* __restrict__ WqkvT,
                                                u16* __restrict__ WoT, const float* __restrict__ maskp,
                                                u32* __restrict__ flags) {
  __shared__ float tls[32][33];
  int bid = blockIdx.x;
  if (bid < 4096) {
    int i = bid * 256 + threadIdx.x;  // one float4 per thread
    float4_t x = ((const float4_t*)X)[i];
    union { u32 u[2]; u64 ll; } o;
    o.u[0] = pk2(x[0], x[1]);
    o.u[1] = pk2(x[2], x[3]);
    ((u64*)Xb)[i] = o.ll;
  } else if (bid < 8192) {
    int t = bid - 4096;
    int mat = t >> 10, tile = t & 1023;
    const float* W = (mat == 0) ? Wq : (mat == 1) ? Wk : (mat == 2) ? Wv : Wo;
    u16* WT = (mat < 3) ? WqkvT + ((size_t)mat << 20) : WoT;
    int tx = threadIdx.x & 31, ty = threadIdx.x >> 5;  // 32 x 8
    int c0 = (tile & 31) * 32, r0 = (tile >> 5) * 32;  // r0: k, c0: n
    #pragma unroll
    for (int i = 0; i < 4; ++i)
      tls[ty + i * 8][tx] = W[(r0 + ty + i * 8) * 1024 + c0 + tx];
    __syncthreads();
    #pragma unroll
    for (int i = 0; i < 4; ++i)
      WT[(size_t)(c0 + ty + i * 8) * 1024 + r0 + tx] = f2bf(tls[tx][ty + i * 8]);
  } else {
    // all-ones detection for attention mask, one block per batch
    int b = bid - 8192;
    const float* mb = maskp + (b << 11) + threadIdx.x * 8;
    bool ok = true;
    #pragma unroll
    for (int i = 0; i < 8; ++i) ok &= (mb[i] == 1.0f);
    u64 bal = __ballot(ok);
    int w = threadIdx.x >> 6;
    if ((threadIdx.x & 63) == 0) tls[0][w] = (bal == ~0ull) ? 1.0f : 0.0f;
    __syncthreads();
    if (threadIdx.x == 0)
      flags[b] = (tls[0][0] != 0.0f && tls[0][1] != 0.0f &&
                  tls[0][2] != 0.0f && tls[0][3] != 0.0f) ? 1u : 0u;
  }
}

// ---------- GEMM: 128x128 C-tile, 4 waves each 64x64, BK=64, VGPR-pipelined staging ----------
// mode 4 (fused QKV, 768 blocks): col block 0->Q(x0.125*log2e) o0 [B,H,S,64], 1->K o1,
//   2->V o2 [B,H,64,S] (transposed). mode 3 (O-proj, 256 blocks): fp32 out o0.
__global__ __launch_bounds__(256) void gemm128(const u16* __restrict__ A, const u16* __restrict__ BT,
                                               const float* __restrict__ bias0, const float* __restrict__ bias1,
                                               const float* __restrict__ bias2,
                                               void* __restrict__ o0, void* __restrict__ o1, void* __restrict__ o2,
                                               int mode) {
  __shared__ __align__(16) u16 Als[128 * 64];  // 16 KB
  __shared__ __align__(16) u16 Bls[128 * 64];  // 16 KB
  int g = blockIdx.x, m0t, n0t;
  if (mode == 4) {  // 768 blocks: panels of 16 m-tiles x 24 n-tiles
    int mh = g / 384, r = g - mh * 384;
    n0t = r >> 4;
    m0t = mh * 16 + (r & 15);
  } else {          // 256 blocks
    m0t = g & 31;
    n0t = g >> 5;
  }
  const int m0 = m0t * 128, n0 = n0t * 128;
  const int lane = threadIdx.x & 63, wave = threadIdx.x >> 6;
  const int quad = lane >> 4, c = lane & 15;
  const int wm = wave >> 1, wn = wave & 1;

  // staging lanes: 8 rows x 8 chunks(16B) per call; wave covers 32 rows via 4 calls
  const int srow = lane >> 3, schunk = lane & 7;
  int soff[4], dst[4];
  #pragma unroll
  for (int q = 0; q < 4; ++q) {
    int r = wave * 32 + q * 8 + srow;
    soff[q] = r * 1024 + (schunk << 3);                 // linear global
    dst[q]  = r * 64 + ((schunk ^ (r & 7)) << 3);       // XOR-swizzled LDS dest
  }
  const u16* gA = A + (size_t)m0 * 1024;
  const u16* gB = BT + (size_t)n0 * 1024;

  int ar[2][4], br[2][4];
  #pragma unroll
  for (int ko = 0; ko < 2; ++ko) {
    #pragma unroll
    for (int i = 0; i < 4; ++i) {
      int rowa = wm * 64 + i * 16 + c;
      ar[ko][i] = rowa * 64 + (((ko * 4 + quad) ^ (rowa & 7)) << 3);
      int rowb = wn * 64 + i * 16 + c;
      br[ko][i] = rowb * 64 + (((ko * 4 + quad) ^ (rowb & 7)) << 3);
    }
  }

  // prefetch slab 0 into VGPRs
  short8_t ra[4], rb[4];
  #pragma unroll
  for (int q = 0; q < 4; ++q) ra[q] = *(const short8_t*)(gA + soff[q]);
  #pragma unroll
  for (int q = 0; q < 4; ++q) rb[q] = *(const short8_t*)(gB + soff[q]);

  float4_t acc[4][4] = {};
  for (int k0 = 0; k0 < 1024; k0 += 64) {
    // commit prefetched slab to LDS
    #pragma unroll
    for (int q = 0; q < 4; ++q) *(short8_t*)&Als[dst[q]] = ra[q];
    #pragma unroll
    for (int q = 0; q < 4; ++q) *(short8_t*)&Bls[dst[q]] = rb[q];
    __syncthreads();
    // issue next slab's loads now; latency hides under the 32 MFMAs below
    if (k0 < 960) {
      #pragma unroll
      for (int q = 0; q < 4; ++q) ra[q] = *(const short8_t*)(gA + soff[q] + k0 + 64);
      #pragma unroll
      for (int q = 0; q < 4; ++q) rb[q] = *(const short8_t*)(gB + soff[q] + k0 + 64);
    }
    #pragma unroll
    for (int ko = 0; ko < 2; ++ko) {
      short8_t af[4], bfr[4];
      #pragma unroll
      for (int i = 0; i < 4; ++i) af[i] = *(const short8_t*)&Als[ar[ko][i]];
      #pragma unroll
      for (int j = 0; j < 4; ++j) bfr[j] = *(const short8_t*)&Bls[br[ko][j]];
      #pragma unroll
      for (int i = 0; i < 4; ++i)
        #pragma unroll
        for (int j = 0; j < 4; ++j)
          acc[i][j] = __builtin_amdgcn_mfma_f32_16x16x32_bf16(af[i], bfr[j], acc[i][j], 0, 0, 0);
    }
    __syncthreads();  // all reads done before next commit (single LDS buffer)
  }

  const int mrow = m0 + wm * 64, ncol = n0 + wn * 64;
  if (mode == 3) {
    float* o = (float*)o0;
    #pragma unroll
    for (int i = 0; i < 4; ++i) {
      #pragma unroll
      for (int j = 0; j < 4; ++j) {
        int colb = ncol + j * 16 + c;
        float bv = bias0[colb];
        int rowb = mrow + i * 16 + quad * 4;
        #pragma unroll
        for (int r = 0; r < 4; ++r)
          o[(size_t)(rowb + r) * 1024 + colb] = acc[i][j][r] + bv;
      }
    }
  } else {
    #pragma unroll
    for (int j = 0; j < 4; ++j) {
      int colb = ncol + j * 16 + c;     // 0..3071
      int which = colb >> 10;           // 0:Q 1:K 2:V (uniform per j)
      int n1 = colb & 1023, h = n1 >> 6, d = n1 & 63;
      const float* bp = (which == 0) ? bias0 : (which == 1 ? bias1 : bias2);
      float bv = bp[n1];
      #pragma unroll
      for (int i = 0; i < 4; ++i) {
        int rowb = mrow + i * 16 + quad * 4;
        int b = rowb >> 11, s = rowb & 2047;
        if (which == 2) {
          u16* o = (u16*)o2 + (((size_t)(b * 16 + h) * 64 + d) * 2048 + s);
          union { u32 u[2]; u64 ll; } ov;
          ov.u[0] = pk2(acc[i][j][0] + bv, acc[i][j][1] + bv);
          ov.u[1] = pk2(acc[i][j][2] + bv, acc[i][j][3] + bv);
          *(u64*)o = ov.ll;
        } else {
          // Q pre-scale folds softmax's LOG2E: 0.125 * 1.4426950408889634
          float sc = (which == 0) ? 0.18033688011112042f : 1.0f;
          u16* o = (u16*)((which == 0) ? o0 : o1);
          #pragma unroll
          for (int r = 0; r < 4; ++r)
            o[(((size_t)(b * 16 + h) * 2048 + (s + r)) << 6) + d] = f2bf((acc[i][j][r] + bv) * sc);
        }
      }
    }
  }
}

// P^T C-layout -> 16x16x32 B-operand layout via gfx950 permlane swaps (VALU pipe,
// replaces 16 ds_bpermute + 8 cndmask per tile -> kills SQ_LDS_BANK_CONFLICT).
// Derivation: lane (quad q, col c) holds, per kc: a0=keys q*4+{0,1}, a1=q*4+{2,3},
// b0=16+q*4+{0,1}, b1=16+q*4+{2,3} (packed bf16 pairs). B-operand needs lane q to
// hold keys q*8+{0..7}: w0 rows=[a@q0,a@q2,b@q0,b@q2], w2 rows=[a@q1,a@q3,b@q1,b@q3]
// = permlane16_swap(permlane32_swap(a0,b0)); same for (a1,b1)->(w1,w3).
__device__ inline short8_t p_to_b_swap(const float* p) {
  u32 a0 = pk2(p[0], p[1]), a1 = pk2(p[2], p[3]);
  u32 b0 = pk2(p[4], p[5]), b1 = pk2(p[6], p[7]);
  asm("v_permlane32_swap_b32 %0, %1" : "+v"(a0), "+v"(b0));
  asm("v_permlane32_swap_b32 %0, %1" : "+v"(a1), "+v"(b1));
  asm("v_permlane16_swap_b32 %0, %1" : "+v"(a0), "+v"(b0));
  asm("v_permlane16_swap_b32 %0, %1" : "+v"(a1), "+v"(b1));
  union { u32 u[4]; short8_t v; } pf;
  pf.u[0] = a0; pf.u[1] = a1; pf.u[2] = b0; pf.u[3] = b1;
  return pf.v;
}

// ---------- flash attention (round-0 structure restored): 64-query tile per block,
// dbuf LDS, VGPR-prefetch staging, 1 barrier/tile ----------
// Q,K: [B,H,S,64] bf16 (Q pre-scaled 0.125*log2e); VT: [B,H,64,S]; ctx: [B,S,1024] bf16.
// Grid 1024 x 256: block = (bh, 64-query tile qt); heavy tiles first, pairs (g,g+512)
// sum to 31 tiles. 4 waves each own 16 queries. r2 lesson: direct-global fragment
// reads are L2-latency-bound (129us vs 67us) -- LDS staging + prefetch is right.
// New vs round 0: (a) permlane-based P transform (no bpermute / bank conflicts),
// (b) log2e pre-folded into Q (no fma per element), (c) all-ones mask fast path.
__global__ __launch_bounds__(256, 4) void attn_kernel(const u16* __restrict__ Q, const u16* __restrict__ K,
                                                      const u16* __restrict__ VT, const float* __restrict__ mask,
                                                      const u32* __restrict__ flags, u16* __restrict__ ctx) {
  __shared__ __align__(16) u16 Kls[2 * 64 * 64];  // 2 x 8 KB, [key][d] swizzled
  __shared__ __align__(16) u16 Vls[2 * 64 * 64];  // 2 x 8 KB, [d][key] swizzled
  const float C1 = 10000.0f * 1.4426950408889634f;
  int w = threadIdx.x >> 6, lane = threadIdx.x & 63;
  int quad = lane >> 4, c = lane & 15;
  int g = blockIdx.x;
  int bh = (g & 7) * 4 + ((g >> 3) & 3);
  int u = g >> 5;                            // 0..31
  int qt = (u < 16) ? (31 - u) : (u - 16);   // heavy first; pairs (g,g+512) sum to 31
  int b = bh >> 4, h = bh & 15;
  bool ones = flags && (flags[b] != 0);
  const u16* Kp = K + ((size_t)bh << 17);
  const u16* Vp = VT + ((size_t)bh << 17);
  const float* mp = mask + (b << 11);
  int q0 = qt * 64 + w * 16;

  // Q^T B-operand fragment (16 queries per wave)
  const u16* Qp = Q + (((size_t)bh * 2048 + q0 + c) << 6) + quad * 8;
  short8_t qf0 = *(const short8_t*)(Qp);
  short8_t qf1 = *(const short8_t*)(Qp + 32);

  // staging: 64 rows x 8 chunks(16B) per tile; wave w covers rows w*16..+15 (2 calls)
  const int srow = lane >> 3, schunk = lane & 7;
  const u16* gK[2]; const u16* gV[2]; int dK[2], dV[2];
  #pragma unroll
  for (int i = 0; i < 2; ++i) {
    int R = w * 16 + i * 8 + srow;           // key row (K) / d row (V)
    gK[i] = Kp + R * 64 + (schunk << 3);                 // linear source
    dK[i] = R * 64 + ((schunk ^ (R & 7)) << 3);          // swizzled dest
    gV[i] = Vp + (size_t)R * 2048 + (schunk << 3);
    dV[i] = R * 64 + ((schunk ^ (R & 7)) << 3);
  }

  // fragment read offsets with matching swizzle
  int koff[4][2];
  #pragma unroll
  for (int kg = 0; kg < 4; ++kg) {
    int r = kg * 16 + c;
    #pragma unroll
    for (int ko = 0; ko < 2; ++ko)
      koff[kg][ko] = r * 64 + (((ko * 4 + quad) ^ (r & 7)) << 3);
  }
  int voff[4][2];
  #pragma unroll
  for (int dblk = 0; dblk < 4; ++dblk) {
    int d = dblk * 16 + c;
    #pragma unroll
    for (int kc = 0; kc < 2; ++kc)
      voff[dblk][kc] = d * 64 + (((kc * 4 + quad) ^ (d & 7)) << 3);
  }

  int ke[8];
  #pragma unroll
  for (int e = 0; e < 8; ++e) ke[e] = ((e >> 2) << 4) + quad * 4 + (e & 3);
  int thr = w * 16 + c;  // causal threshold within the diagonal tile

  float4_t O[4] = {};
  float l = 0.0f;

  // prefetch tile 0 into VGPRs
  short8_t kreg[2], vreg[2];
  #pragma unroll
  for (int i = 0; i < 2; ++i) { kreg[i] = *(const short8_t*)(gK[i]); vreg[i] = *(const short8_t*)(gV[i]); }

  for (int t = 0; t <= qt; ++t) {
    int kb = t << 6;
    int bufo = (t & 1) << 12;  // 4096 u16 per buffer
    #pragma unroll
    for (int i = 0; i < 2; ++i) *(short8_t*)&Kls[bufo + dK[i]] = kreg[i];
    #pragma unroll
    for (int i = 0; i < 2; ++i) *(short8_t*)&Vls[bufo + dV[i]] = vreg[i];
    __syncthreads();
    if (t < qt) {  // issue tile t+1 loads; land during this tile's compute
      int kb2 = (t + 1) << 6;
      #pragma unroll
      for (int i = 0; i < 2; ++i) {
        kreg[i] = *(const short8_t*)(gK[i] + (size_t)kb2 * 64);
        vreg[i] = *(const short8_t*)(gV[i] + kb2);
      }
    }
    // ---- S^T = K_tile @ Q^T (8 MFMA) ----
    float4_t s[4];
    #pragma unroll
    for (int kg = 0; kg < 4; ++kg) {
      short8_t k0 = *(const short8_t*)&Kls[bufo + koff[kg][0]];
      short8_t k1 = *(const short8_t*)&Kls[bufo + koff[kg][1]];
      float4_t a = {};
      a = __builtin_amdgcn_mfma_f32_16x16x32_bf16(k0, qf0, a, 0, 0, 0);
      a = __builtin_amdgcn_mfma_f32_16x16x32_bf16(k1, qf1, a, 0, 0, 0);
      s[kg] = a;
    }
    // ---- mask (skipped on all-ones) + fixed-base softmax + C->B transform ----
    float4_t mpl[4];
    if (!ones) {
      #pragma unroll
      for (int kg = 0; kg < 4; ++kg)
        mpl[kg] = (*(const float4_t*)(mp + kb + kg * 16 + quad * 4) - 1.0f) * C1;
    }
    bool diag = (t == qt);
    short8_t pf[2];
    #pragma unroll
    for (int kc = 0; kc < 2; ++kc) {
      float p[8];
      #pragma unroll
      for (int e = 0; e < 8; ++e) {
        int kg = kc * 2 + (e >> 2);
        p[e] = s[kg][e & 3];                // log2e already folded into Q
        if (!ones) p[e] += mpl[kg][e & 3];
      }
      if (diag) {
        #pragma unroll
        for (int e = 0; e < 8; ++e) {
          int ko2 = kc * 32 + ke[e];
          p[e] = (ko2 > thr) ? -50.0f : p[e];
        }
      }
      #pragma unroll
      for (int e = 0; e < 8; ++e) {
        float pe = exp2f(p[e]);
        p[e] = pe;
        l += pe;
      }
      pf[kc] = p_to_b_swap(p);
    }
    // ---- ctx^T += V^T_tile @ P^T (8 MFMA) ----
    #pragma unroll
    for (int dblk = 0; dblk < 4; ++dblk) {
      #pragma unroll
      for (int kc = 0; kc < 2; ++kc) {
        short8_t vf = *(const short8_t*)&Vls[bufo + voff[dblk][kc]];
        O[dblk] = __builtin_amdgcn_mfma_f32_16x16x32_bf16(vf, pf[kc], O[dblk], 0, 0, 0);
      }
    }
    // no trailing barrier: next tile writes the OTHER buffer; its leading barrier
    // orders those writes after every wave's reads of this buffer.
  }
  // ---- epilogue: reduce l across quads, normalize, store ----
  l += __shfl_xor(l, 16);
  l += __shfl_xor(l, 32);
  float rl = 1.0f / l;
  u16* op = ctx + ((size_t)(b * 2048 + q0 + c) * 1024 + h * 64 + quad * 4);
  #pragma unroll
  for (int dblk = 0; dblk < 4; ++dblk) {
    union { u32 uu[2]; u64 ll; } ov;
    ov.uu[0] = pk2(O[dblk][0] * rl, O[dblk][1] * rl);
    ov.uu[1] = pk2(O[dblk][2] * rl, O[dblk][3] * rl);
    *(u64*)(op + dblk * 16) = ov.ll;
  }
}

// ---------- launch ----------
extern "C" void kernel_launch(void* const* d_in, const int* in_sizes, int n_in,
                              void* d_out, int out_size, void* d_ws, size_t ws_size,
                              hipStream_t stream) {
  const float* X    = (const float*)d_in[0];
  const float* mask = (const float*)d_in[1];
  const float* Wq   = (const float*)d_in[2];
  const float* bq   = (const float*)d_in[3];
  const float* Wk   = (const float*)d_in[4];
  const float* bk   = (const float*)d_in[5];
  const float* Wv   = (const float*)d_in[6];
  const float* bv   = (const float*)d_in[7];
  const float* Wo   = (const float*)d_in[8];
  const float* bo   = (const float*)d_in[9];

  char* w = (char*)d_ws;
  u16* Xb     = (u16*)(w);                 // 8 MB  [4096,1024] bf16
  u16* WqkvT  = (u16*)(w + (8ull  << 20)); // 6 MB  [3072,1024] bf16 (Q|K|V transposed)
  u16* WoT    = (u16*)(w + (14ull << 20)); // 2 MB  [1024,1024] bf16
  u16* Qb     = (u16*)(w + (16ull << 20)); // 8 MB [B,H,S,64]
  u16* Kb     = (u16*)(w + (24ull << 20)); // 8 MB [B,H,S,64]
  u16* VTb    = (u16*)(w + (32ull << 20)); // 8 MB [B,H,64,S]
  u16* Ctx    = (u16*)(w + (40ull << 20)); // 8 MB [4096,1024]
  u32* flags  = (ws_size >= (48ull << 20) + 8) ? (u32*)(w + (48ull << 20)) : nullptr;

  prologue<<<flags ? 8194 : 8192, 256, 0, stream>>>(X, Wq, Wk, Wv, Wo, Xb, WqkvT, WoT, mask, flags);
  gemm128<<<768, 256, 0, stream>>>(Xb, WqkvT, bq, bk, bv, Qb, Kb, VTb, 4);
  attn_kernel<<<1024, 256, 0, stream>>>(Qb, Kb, VTb, mask, flags, Ctx);
  gemm128<<<256, 256, 0, stream>>>(Ctx, WoT, bo, bo, bo, d_out, d_out, d_out, 3);
}